// Round 7
// baseline (78.608 us; speedup 1.0000x reference)
//
#include <hip/hip_runtime.h>

#define PI_F 3.14159265358979323846f

#define D0 768
#define D1 512
#define D2 1024
#define KTOT 2304

// ---- d_ws layout ----
// ushort idx [0, 73728): Bt_hi  [32 cols][2304 k]  (block-diagonal W^T, bf16 hi)
// ushort idx [73728, 147456): Bt_lo (bf16 residual)
// float idx (from ws base):
#define U_OFF   73728   // 12 gates * 4 floats
#define CRY_OFF 73776   // 6 * 2 floats
#define ANG_OFF 73792   // 16384*6 floats (angles)

typedef short short8 __attribute__((ext_vector_type(8)));
typedef float f32x4 __attribute__((ext_vector_type(4)));
typedef unsigned int uint4v __attribute__((ext_vector_type(4)));

// ---------------- prep kernels ----------------

// Bt[c][k]: block-diagonal weights, col-major (contiguous k), bf16 hi/lo split
__global__ void prep_bt(const float* __restrict__ W0, const float* __restrict__ W1,
                        const float* __restrict__ W2, unsigned short* __restrict__ bt_hi,
                        unsigned short* __restrict__ bt_lo) {
    int k = blockIdx.x * 256 + threadIdx.x;  // 0..2303 (grid.x = 9)
    int c = blockIdx.y;                       // 0..31
    float v = 0.0f;
    if (c < 6)       { if (k < 768)              v = W0[k * 6 + c]; }
    else if (c < 12) { if (k >= 768 && k < 1280) v = W1[(k - 768) * 6 + (c - 6)]; }
    else if (c < 18) { if (k >= 1280)            v = W2[(k - 1280) * 6 + (c - 12)]; }
    unsigned int u = __float_as_uint(v);
    float hif = __uint_as_float(u & 0xFFFF0000u);
    float lo = v - hif;  // exact
    bt_hi[c * KTOT + k] = (unsigned short)(u >> 16);
    bt_lo[c * KTOT + k] = (unsigned short)(__float_as_uint(lo) >> 16);
}

__global__ void prep_consts(const float* __restrict__ qw, float* __restrict__ wsf) {
    int t = threadIdx.x;
    if (t < 12) {
        int g = t;  // layer*6 + qubit
        float ca, sa, cb, sb, cc, sc;
        sincosf(0.5f * qw[g * 3 + 0], &sa, &ca);
        sincosf(0.5f * qw[g * 3 + 1], &sb, &cb);
        sincosf(0.5f * qw[g * 3 + 2], &sc, &cc);
        // U = Rz(g)*Ry(b)*Rx(a); SU(2) row0 = (u00, u01)
        float m00r = cb * ca, m00i = sb * sa;
        float m01r = -sb * ca, m01i = -cb * sa;
        float* u4 = wsf + U_OFF + g * 4;
        u4[0] = m00r * cc + m00i * sc;
        u4[1] = m00i * cc - m00r * sc;
        u4[2] = m01r * cc + m01i * sc;
        u4[3] = m01i * cc - m01r * sc;
    } else if (t < 18) {
        int k = t - 12;  // layer*3 + pair
        int l = k / 3, i = (k - l * 3) * 2;
        float c, s;
        sincosf(0.5f * qw[(l * 6 + i) * 3 + 1], &s, &c);
        wsf[CRY_OFF + k * 2 + 0] = c;
        wsf[CRY_OFF + k * 2 + 1] = s;
    }
}

// ---------------- GEMM kernel (MFMA 16x16x32 bf16, bf16x2 split) ----------------

__device__ __forceinline__ unsigned int pkhi(float x, float y) {
    return (__float_as_uint(x) >> 16) | (__float_as_uint(y) & 0xFFFF0000u);
}
__device__ __forceinline__ float truncbf(float x) {
    return __uint_as_float(__float_as_uint(x) & 0xFFFF0000u);
}
__device__ __forceinline__ void split8(float4 x0, float4 x1, short8& hi, short8& lo) {
    uint4v h, l;
    h[0] = pkhi(x0.x, x0.y); h[1] = pkhi(x0.z, x0.w);
    h[2] = pkhi(x1.x, x1.y); h[3] = pkhi(x1.z, x1.w);
    l[0] = pkhi(x0.x - truncbf(x0.x), x0.y - truncbf(x0.y));
    l[1] = pkhi(x0.z - truncbf(x0.z), x0.w - truncbf(x0.w));
    l[2] = pkhi(x1.x - truncbf(x1.x), x1.y - truncbf(x1.y));
    l[3] = pkhi(x1.z - truncbf(x1.z), x1.w - truncbf(x1.w));
    hi = __builtin_bit_cast(short8, h);
    lo = __builtin_bit_cast(short8, l);
}
__device__ __forceinline__ f32x4 mfma16(short8 a, short8 b, f32x4 c) {
    return __builtin_amdgcn_mfma_f32_16x16x32_bf16(a, b, c, 0, 0, 0);
}

__device__ __forceinline__ float fast_tanh(float x) {
    float e = __expf(2.0f * x);
    return 1.0f - 2.0f / (e + 1.0f);
}

__global__ __launch_bounds__(256) void gemm_kernel(
    const float* __restrict__ f0, const float* __restrict__ f1, const float* __restrict__ f2,
    const float* __restrict__ b0, const float* __restrict__ b1, const float* __restrict__ b2,
    const float* __restrict__ fl, const unsigned short* __restrict__ bt_hi,
    const unsigned short* __restrict__ bt_lo, float* __restrict__ ang_out)
{
    const int lane = threadIdx.x & 63;
    const int wave = blockIdx.x * 4 + (threadIdx.x >> 6);  // 1024 waves, 16 rows each
    const int row_base = wave * 16;
    const int c = lane & 15;   // A-row within tile / B-col / D-col
    const int kh = lane >> 4;  // k-subgroup: k-offset kh*8

    f32x4 acc0 = {0.f, 0.f, 0.f, 0.f};  // cols 0..15
    f32x4 acc1 = {0.f, 0.f, 0.f, 0.f};  // cols 16..31 (16,17 used)

    const float* a0 = f0 + (size_t)(row_base + c) * D0 + kh * 8;
    const float* a1 = f1 + (size_t)(row_base + c) * D1 + kh * 8;
    const float* a2 = f2 + (size_t)(row_base + c) * D2 + kh * 8;
    const unsigned short* bh = bt_hi + c * KTOT + kh * 8;
    const unsigned short* bl = bt_lo + c * KTOT + kh * 8;

    // modality 0: global k in [0,768)
#pragma unroll 4
    for (int t = 0; t < 24; ++t) {
        float4 x0 = *(const float4*)(a0 + t * 32);
        float4 x1 = *(const float4*)(a0 + t * 32 + 4);
        short8 ahi, alo; split8(x0, x1, ahi, alo);
        short8 bh0 = *(const short8*)(bh + t * 32);
        short8 bl0 = *(const short8*)(bl + t * 32);
        acc0 = mfma16(ahi, bh0, acc0);
        acc0 = mfma16(alo, bh0, acc0);
        acc0 = mfma16(ahi, bl0, acc0);
    }
    // modality 1: global k in [768,1280)
#pragma unroll 4
    for (int t = 0; t < 16; ++t) {
        float4 x0 = *(const float4*)(a1 + t * 32);
        float4 x1 = *(const float4*)(a1 + t * 32 + 4);
        short8 ahi, alo; split8(x0, x1, ahi, alo);
        short8 bh0 = *(const short8*)(bh + 768 + t * 32);
        short8 bl0 = *(const short8*)(bl + 768 + t * 32);
        acc0 = mfma16(ahi, bh0, acc0);
        acc0 = mfma16(alo, bh0, acc0);
        acc0 = mfma16(ahi, bl0, acc0);
    }
    // modality 2: global k in [1280,2304); cols 12..17 -> tile0 cols 12-15 + tile1 cols 16-17
#pragma unroll 4
    for (int t = 0; t < 32; ++t) {
        float4 x0 = *(const float4*)(a2 + t * 32);
        float4 x1 = *(const float4*)(a2 + t * 32 + 4);
        short8 ahi, alo; split8(x0, x1, ahi, alo);
        short8 bh0 = *(const short8*)(bh + 1280 + t * 32);
        short8 bl0 = *(const short8*)(bl + 1280 + t * 32);
        short8 bh1 = *(const short8*)(bh + 16 * KTOT + 1280 + t * 32);
        short8 bl1 = *(const short8*)(bl + 16 * KTOT + 1280 + t * 32);
        acc0 = mfma16(ahi, bh0, acc0);
        acc0 = mfma16(alo, bh0, acc0);
        acc0 = mfma16(ahi, bl0, acc0);
        acc1 = mfma16(ahi, bh1, acc1);
        acc1 = mfma16(alo, bh1, acc1);
        acc1 = mfma16(ahi, bl1, acc1);
    }

    // ---- epilogue: tanh + fusion-weighted sum across modality cols ----
    float l0 = fl[0], l1 = fl[1], l2 = fl[2];
    float mx = fmaxf(l0, fmaxf(l1, l2));
    float e0 = __expf(l0 - mx), e1 = __expf(l1 - mx), e2 = __expf(l2 - mx);
    float inv = 1.0f / (e0 + e1 + e2);
    float fw0 = e0 * inv, fw1 = e1 * inv, fw2 = e2 * inv;

    float bia, fwm;
    if (c < 6)       { bia = b0[c];      fwm = fw0; }
    else if (c < 12) { bia = b1[c - 6];  fwm = fw1; }
    else             { bia = b2[c - 12]; fwm = fw2; }
    float bia1 = (c < 2) ? b2[4 + c] : 0.f;

    float ang4[4];
#pragma unroll
    for (int r = 0; r < 4; ++r) {
        float vj = fwm * fast_tanh(acc0[r] + bia);
        float v1 = (c < 2) ? fw2 * fast_tanh(acc1[r] + bia1) : 0.f;
        // m2v: lanes 12..15 hold m2 j=0..3; lanes 0,1 hold m2 j=4,5
        float m2v = (c >= 12) ? vj : v1;
        float sh6  = __shfl(vj,  (lane & 48) | ((c + 6) & 15), 64);
        float shm2 = __shfl(m2v, (lane & 48) | ((c < 4 ? c + 12 : c - 4) & 15), 64);
        ang4[r] = PI_F * (vj + sh6 + shm2);
    }
    if (c < 6) {
#pragma unroll
        for (int r = 0; r < 4; ++r)
            ang_out[(size_t)(row_base + kh * 4 + r) * 6 + c] = ang4[r];
    }
}

// ---------------- circuit kernel ----------------

template<int CTRL>
__device__ __forceinline__ float dppmov(float v) {
    return __int_as_float(__builtin_amdgcn_update_dpp(0, __float_as_int(v), CTRL, 0xF, 0xF, true));
}
template<int PAT>
__device__ __forceinline__ float swzf(float v) {
    return __int_as_float(__builtin_amdgcn_ds_swizzle(__float_as_int(v), PAT));
}
template<int M>
__device__ __forceinline__ float xsh(float v) {
    if constexpr (M == 1)       return dppmov<0xB1>(v);
    else if constexpr (M == 2)  return dppmov<0x4E>(v);
    else if constexpr (M == 4)  return swzf<0x101F>(v);
    else if constexpr (M == 8)  return dppmov<0x128>(v);
    else if constexpr (M == 16) return swzf<0x401F>(v);
    else                        return __shfl_xor(v, 32, 64);
}

template<int M>
__device__ __forceinline__ void gateU(float (&re)[2], float (&im)[2], int lane,
                                      float ar, float ai, float br, float bi) {
    const bool hi = (lane & M) != 0;
    const float Ai = hi ? -ai : ai;
    const float Br = hi ? -br : br;
#pragma unroll
    for (int s = 0; s < 2; ++s) {
        float pre = xsh<M>(re[s]);
        float pim = xsh<M>(im[s]);
        float nr = ar * re[s] - Ai * im[s] + Br * pre - bi * pim;
        float ni = ar * im[s] + Ai * re[s] + Br * pim + bi * pre;
        re[s] = nr; im[s] = ni;
    }
}

template<int MC, int MT>
__device__ __forceinline__ void gateCRY(float (&re)[2], float (&im)[2], int lane, float c, float sn) {
    const bool c1 = (lane & MC) != 0;
    const float sg = (lane & MT) ? sn : -sn;
#pragma unroll
    for (int s = 0; s < 2; ++s) {
        float pre = xsh<MT>(re[s]);
        float pim = xsh<MT>(im[s]);
        float nr = fmaf(c, re[s], sg * pre);
        float ni = fmaf(c, im[s], sg * pim);
        re[s] = c1 ? nr : re[s];
        im[s] = c1 ? ni : im[s];
    }
}

template<int I>
__device__ __forceinline__ void l1gate(float (&re)[2], float (&im)[2], int lane,
                                       const float* __restrict__ ws) {
    constexpr int M = 32 >> I;
    gateU<M>(re, im, lane, ws[U_OFF + (6 + I) * 4 + 0], ws[U_OFF + (6 + I) * 4 + 1],
             ws[U_OFF + (6 + I) * 4 + 2], ws[U_OFF + (6 + I) * 4 + 3]);
}
template<int L, int P>
__device__ __forceinline__ void cryGate(float (&re)[2], float (&im)[2], int lane,
                                        const float* __restrict__ ws) {
    constexpr int MC = 32 >> (2 * P);
    constexpr int MT = 16 >> (2 * P);
    gateCRY<MC, MT>(re, im, lane, ws[CRY_OFF + (L * 3 + P) * 2 + 0],
                    ws[CRY_OFF + (L * 3 + P) * 2 + 1]);
}

__device__ __forceinline__ void buildState(const float (&ang)[6], int lane,
                                           const float* __restrict__ ws,
                                           float& reO, float& imO) {
    float pr, pi;
#pragma unroll
    for (int i = 0; i < 6; ++i) {
        float cq, sq;
        __sincosf(0.5f * ang[i], &sq, &cq);
        const float ar = ws[U_OFF + i * 4 + 0];
        const float ai = ws[U_OFF + i * 4 + 1];
        const float br = ws[U_OFF + i * 4 + 2];
        const float bi = ws[U_OFF + i * 4 + 3];
        float vloR = ar * cq + br * sq;
        float vloI = ai * cq + bi * sq;
        float vhiR = ar * sq - br * cq;
        float vhiI = bi * cq - ai * sq;
        bool hi = (lane & (32 >> i)) != 0;
        float vr = hi ? vhiR : vloR;
        float vi = hi ? vhiI : vloI;
        if (i == 0) { pr = vr; pi = vi; }
        else { float t = pr * vr - pi * vi; pi = pr * vi + pi * vr; pr = t; }
    }
    reO = pr; imO = pi;
}

__global__ __launch_bounds__(256, 8) void circuit_kernel(
    const float* __restrict__ ws, const float* __restrict__ ang_buf, float* __restrict__ out)
{
    const int lane = threadIdx.x & 63;
    const int wave = blockIdx.x * 4 + (threadIdx.x >> 6);  // 8192 waves
    const int s0 = wave * 2;

    const float* aA = ang_buf + (size_t)s0 * 6;
    float angA[6], angB[6];
#pragma unroll
    for (int j = 0; j < 6; ++j) { angA[j] = aA[j]; angB[j] = aA[6 + j]; }

    const int sigma = lane ^ ((lane >> 1) & 0x1F) ^ ((lane >> 5) & 1);

    float re[2], im[2];
    buildState(angA, lane, ws, re[0], im[0]);  // encoding + layer-0 rotations fused
    buildState(angB, lane, ws, re[1], im[1]);

    re[0] = __shfl(re[0], sigma, 64); im[0] = __shfl(im[0], sigma, 64);
    re[1] = __shfl(re[1], sigma, 64); im[1] = __shfl(im[1], sigma, 64);
    cryGate<0,0>(re, im, lane, ws); cryGate<0,1>(re, im, lane, ws); cryGate<0,2>(re, im, lane, ws);

    l1gate<0>(re, im, lane, ws); l1gate<1>(re, im, lane, ws); l1gate<2>(re, im, lane, ws);
    l1gate<3>(re, im, lane, ws); l1gate<4>(re, im, lane, ws); l1gate<5>(re, im, lane, ws);
    re[0] = __shfl(re[0], sigma, 64); im[0] = __shfl(im[0], sigma, 64);
    re[1] = __shfl(re[1], sigma, 64); im[1] = __shfl(im[1], sigma, 64);
    cryGate<1,0>(re, im, lane, ws); cryGate<1,1>(re, im, lane, ws); cryGate<1,2>(re, im, lane, ws);

#pragma unroll
    for (int s = 0; s < 2; ++s) {
        float p = fmaf(re[s], re[s], im[s] * im[s]);
        float q;
        q = xsh<1>(p);  p = (lane & 1)  ? (q - p) : (p + q);
        q = xsh<2>(p);  p = (lane & 2)  ? (q - p) : (p + q);
        q = xsh<4>(p);  p = (lane & 4)  ? (q - p) : (p + q);
        q = xsh<8>(p);  p = (lane & 8)  ? (q - p) : (p + q);
        q = xsh<16>(p); p = (lane & 16) ? (q - p) : (p + q);
        q = xsh<32>(p); p = (lane & 32) ? (q - p) : (p + q);
        if (__popc(lane) == 1)
            out[(size_t)(s0 + s) * 6 + (6 - __ffs(lane))] = p;
    }
}

extern "C" void kernel_launch(void* const* d_in, const int* in_sizes, int n_in,
                              void* d_out, int out_size, void* d_ws, size_t ws_size,
                              hipStream_t stream) {
    const float* f0 = (const float*)d_in[0];
    const float* W0 = (const float*)d_in[1];
    const float* b0 = (const float*)d_in[2];
    const float* f1 = (const float*)d_in[3];
    const float* W1 = (const float*)d_in[4];
    const float* b1 = (const float*)d_in[5];
    const float* f2 = (const float*)d_in[6];
    const float* W2 = (const float*)d_in[7];
    const float* b2 = (const float*)d_in[8];
    const float* qw = (const float*)d_in[9];
    const float* fl = (const float*)d_in[10];
    float* out = (float*)d_out;

    unsigned short* bt_hi = (unsigned short*)d_ws;
    unsigned short* bt_lo = bt_hi + 73728;
    float* wsf = (float*)d_ws;
    float* ang = wsf + ANG_OFF;

    prep_bt<<<dim3(9, 32), 256, 0, stream>>>(W0, W1, W2, bt_hi, bt_lo);
    prep_consts<<<1, 64, 0, stream>>>(qw, wsf);
    gemm_kernel<<<256, 256, 0, stream>>>(f0, f1, f2, b0, b1, b2, fl, bt_hi, bt_lo, ang);
    circuit_kernel<<<2048, 256, 0, stream>>>(wsf, ang, out);
}

// Round 10
// 68.123 us; speedup vs baseline: 1.1539x; 1.1539x over previous
//
#include <hip/hip_runtime.h>

#define PI_F 3.14159265358979323846f

#define D0 768
#define D1 512
#define D2 1024
#define KTOT 2304

// ---- d_ws layout ----
// ushort idx [0, 73728):      Bt_hi [32 cols][2304 k] (block-diagonal W^T, bf16 hi)
// ushort idx [73728, 147456): Bt_lo (bf16 residual)
// float idx (from ws base):
#define U_OFF    73728                    // 12 gates * 4 floats
#define CRY_OFF  73776                    // 6 * 2 floats
#define PACC_OFF 73856                    // 4096 jobs * 512 floats = 8 MB
#define ANG_OFF  (PACC_OFF + 4096 * 512)  // 16384*6 floats

typedef short short8 __attribute__((ext_vector_type(8)));
typedef float f32x4 __attribute__((ext_vector_type(4)));
typedef unsigned int uint4v __attribute__((ext_vector_type(4)));

// ---------------- prep kernels (verbatim round 7, verified) ----------------

__global__ void prep_bt(const float* __restrict__ W0, const float* __restrict__ W1,
                        const float* __restrict__ W2, unsigned short* __restrict__ bt_hi,
                        unsigned short* __restrict__ bt_lo) {
    int k = blockIdx.x * 256 + threadIdx.x;  // 0..2303 (grid.x = 9)
    int c = blockIdx.y;                       // 0..31
    float v = 0.0f;
    if (c < 6)       { if (k < 768)              v = W0[k * 6 + c]; }
    else if (c < 12) { if (k >= 768 && k < 1280) v = W1[(k - 768) * 6 + (c - 6)]; }
    else if (c < 18) { if (k >= 1280)            v = W2[(k - 1280) * 6 + (c - 12)]; }
    unsigned int u = __float_as_uint(v);
    float hif = __uint_as_float(u & 0xFFFF0000u);
    float lo = v - hif;  // exact residual
    bt_hi[c * KTOT + k] = (unsigned short)(u >> 16);
    bt_lo[c * KTOT + k] = (unsigned short)(__float_as_uint(lo) >> 16);
}

__global__ void prep_consts(const float* __restrict__ qw, float* __restrict__ wsf) {
    int t = threadIdx.x;
    if (t < 12) {
        int g = t;  // layer*6 + qubit
        float ca, sa, cb, sb, cc, sc;
        sincosf(0.5f * qw[g * 3 + 0], &sa, &ca);
        sincosf(0.5f * qw[g * 3 + 1], &sb, &cb);
        sincosf(0.5f * qw[g * 3 + 2], &sc, &cc);
        float m00r = cb * ca, m00i = sb * sa;
        float m01r = -sb * ca, m01i = -cb * sa;
        float* u4 = wsf + U_OFF + g * 4;
        u4[0] = m00r * cc + m00i * sc;
        u4[1] = m00i * cc - m00r * sc;
        u4[2] = m01r * cc + m01i * sc;
        u4[3] = m01i * cc - m01r * sc;
    } else if (t < 18) {
        int k = t - 12;  // layer*3 + pair
        int l = k / 3, i = (k - l * 3) * 2;
        float c, s;
        sincosf(0.5f * qw[(l * 6 + i) * 3 + 1], &s, &c);
        wsf[CRY_OFF + k * 2 + 0] = c;
        wsf[CRY_OFF + k * 2 + 1] = s;
    }
}

// ---------------- helpers ----------------

__device__ __forceinline__ unsigned int pkhi(float x, float y) {
    return (__float_as_uint(x) >> 16) | (__float_as_uint(y) & 0xFFFF0000u);
}
__device__ __forceinline__ float truncbf(float x) {
    return __uint_as_float(__float_as_uint(x) & 0xFFFF0000u);
}
__device__ __forceinline__ void split8(float4 x0, float4 x1, short8& hi, short8& lo) {
    uint4v h, l;
    h[0] = pkhi(x0.x, x0.y); h[1] = pkhi(x0.z, x0.w);
    h[2] = pkhi(x1.x, x1.y); h[3] = pkhi(x1.z, x1.w);
    l[0] = pkhi(x0.x - truncbf(x0.x), x0.y - truncbf(x0.y));
    l[1] = pkhi(x0.z - truncbf(x0.z), x0.w - truncbf(x0.w));
    l[2] = pkhi(x1.x - truncbf(x1.x), x1.y - truncbf(x1.y));
    l[3] = pkhi(x1.z - truncbf(x1.z), x1.w - truncbf(x1.w));
    hi = __builtin_bit_cast(short8, h);
    lo = __builtin_bit_cast(short8, l);
}
__device__ __forceinline__ f32x4 mfma16(short8 a, short8 b, f32x4 c) {
    return __builtin_amdgcn_mfma_f32_16x16x32_bf16(a, b, c, 0, 0, 0);
}
__device__ __forceinline__ float fast_tanh(float x) {
    float e = __expf(2.0f * x);
    return 1.0f - 2.0f / (e + 1.0f);
}

template<int CTRL>
__device__ __forceinline__ float dppmov(float v) {
    return __int_as_float(__builtin_amdgcn_update_dpp(0, __float_as_int(v), CTRL, 0xF, 0xF, true));
}
template<int PAT>
__device__ __forceinline__ float swzf(float v) {
    return __int_as_float(__builtin_amdgcn_ds_swizzle(__float_as_int(v), PAT));
}
template<int M>
__device__ __forceinline__ float xsh(float v) {
    if constexpr (M == 1)       return dppmov<0xB1>(v);
    else if constexpr (M == 2)  return dppmov<0x4E>(v);
    else if constexpr (M == 4)  return swzf<0x101F>(v);
    else if constexpr (M == 8)  return dppmov<0x128>(v);
    else if constexpr (M == 16) return swzf<0x401F>(v);
    else                        return __shfl_xor(v, 32, 64);
}

// ---------------- GEMM: split-K=4 through GLOBAL partials (no intra-block comm) ----------------
// job j = 4*blockIdx + (tid>>6); m-tile = j>>2 (16 rows), K-slice ks = j&3 (18 contiguous k-tiles).
// Slice bounds never split a 32-wide tile; per-modality sub-loops have branch-free bodies (R7 shape).

__global__ __launch_bounds__(256) void gemm_kernel(
    const float* __restrict__ f0, const float* __restrict__ f1, const float* __restrict__ f2,
    const unsigned short* __restrict__ bt_hi, const unsigned short* __restrict__ bt_lo,
    float* __restrict__ pacc)
{
    const int tid = threadIdx.x;
    const int lane = tid & 63;
    const int j = blockIdx.x * 4 + (tid >> 6);   // 0..4095
    const int m = j >> 2;                         // 0..1023
    const int ks = j & 3;                         // 0..3
    const int row_base = m * 16;
    const int c = lane & 15;
    const int kh = lane >> 4;

    f32x4 acc0 = {0.f, 0.f, 0.f, 0.f};
    f32x4 acc1 = {0.f, 0.f, 0.f, 0.f};

    const size_t rb = row_base + c;
    const float* a0 = f0 + rb * D0 + kh * 8;
    const float* a1 = f1 + rb * D1 + kh * 8;
    const float* a2 = f2 + rb * D2 + kh * 8;
    const unsigned short* bh = bt_hi + c * KTOT + kh * 8;
    const unsigned short* bl = bt_lo + c * KTOT + kh * 8;

    const int t0 = ks * 18, t1 = t0 + 18;

    // modality 0: tiles [t0, min(t1,24))
    const int e0 = t1 < 24 ? t1 : 24;
#pragma unroll 2
    for (int t = t0; t < e0; ++t) {
        float4 x0 = *(const float4*)(a0 + t * 32);
        float4 x1 = *(const float4*)(a0 + t * 32 + 4);
        short8 ahi, alo; split8(x0, x1, ahi, alo);
        short8 bh0 = *(const short8*)(bh + t * 32);
        short8 bl0 = *(const short8*)(bl + t * 32);
        acc0 = mfma16(ahi, bh0, acc0);
        acc0 = mfma16(alo, bh0, acc0);
        acc0 = mfma16(ahi, bl0, acc0);
    }
    // modality 1: tiles [max(t0,24), min(t1,40))
    const int s1 = t0 > 24 ? t0 : 24;
    const int e1 = t1 < 40 ? t1 : 40;
#pragma unroll 2
    for (int t = s1; t < e1; ++t) {
        float4 x0 = *(const float4*)(a1 + (t - 24) * 32);
        float4 x1 = *(const float4*)(a1 + (t - 24) * 32 + 4);
        short8 ahi, alo; split8(x0, x1, ahi, alo);
        short8 bh0 = *(const short8*)(bh + t * 32);
        short8 bl0 = *(const short8*)(bl + t * 32);
        acc0 = mfma16(ahi, bh0, acc0);
        acc0 = mfma16(alo, bh0, acc0);
        acc0 = mfma16(ahi, bl0, acc0);
    }
    // modality 2: tiles [max(t0,40), t1); cols 16,17 in tile1
    const int s2 = t0 > 40 ? t0 : 40;
#pragma unroll 2
    for (int t = s2; t < t1; ++t) {
        float4 x0 = *(const float4*)(a2 + (t - 40) * 32);
        float4 x1 = *(const float4*)(a2 + (t - 40) * 32 + 4);
        short8 ahi, alo; split8(x0, x1, ahi, alo);
        short8 bh0 = *(const short8*)(bh + t * 32);
        short8 bl0 = *(const short8*)(bl + t * 32);
        short8 bh1 = *(const short8*)(bh + 16 * KTOT + t * 32);
        short8 bl1 = *(const short8*)(bl + 16 * KTOT + t * 32);
        acc0 = mfma16(ahi, bh0, acc0);
        acc0 = mfma16(alo, bh0, acc0);
        acc0 = mfma16(ahi, bl0, acc0);
        acc1 = mfma16(ahi, bh1, acc1);
        acc1 = mfma16(alo, bh1, acc1);
        acc1 = mfma16(ahi, bl1, acc1);
    }

    // store partials to global (coalesced; disjoint per job)
    float* pj = pacc + (size_t)j * 512;
#pragma unroll
    for (int r = 0; r < 4; ++r) {
        pj[r * 64 + lane] = acc0[r];
        pj[(4 + r) * 64 + lane] = acc1[r];
    }
}

// ---------------- reduce + epilogue (R7 epilogue verbatim on summed partials) ----------------

__global__ __launch_bounds__(256) void reduce_kernel(
    const float* __restrict__ b0, const float* __restrict__ b1, const float* __restrict__ b2,
    const float* __restrict__ fl, const float* __restrict__ pacc, float* __restrict__ ang_out)
{
    const int tid = threadIdx.x;
    const int lane = tid & 63;
    const int m = blockIdx.x * 4 + (tid >> 6);   // 0..1023
    const int row_base = m * 16;
    const int c = lane & 15;
    const int kh = lane >> 4;

    const float* pm = pacc + (size_t)m * 4 * 512;
    float a0s[4], a1s[4];
#pragma unroll
    for (int r = 0; r < 4; ++r) {
        float s0 = 0.f, s1v = 0.f;
#pragma unroll
        for (int ks = 0; ks < 4; ++ks) {
            s0  += pm[ks * 512 + r * 64 + lane];
            s1v += pm[ks * 512 + (4 + r) * 64 + lane];
        }
        a0s[r] = s0; a1s[r] = s1v;
    }

    float l0 = fl[0], l1 = fl[1], l2 = fl[2];
    float mx = fmaxf(l0, fmaxf(l1, l2));
    float e0 = __expf(l0 - mx), e1 = __expf(l1 - mx), e2 = __expf(l2 - mx);
    float inv = 1.0f / (e0 + e1 + e2);
    float fw0 = e0 * inv, fw1 = e1 * inv, fw2 = e2 * inv;

    float bia, fwm;
    if (c < 6)       { bia = b0[c];      fwm = fw0; }
    else if (c < 12) { bia = b1[c - 6];  fwm = fw1; }
    else             { bia = b2[c - 12]; fwm = fw2; }
    float bia1 = (c < 2) ? b2[4 + c] : 0.f;

    float ang4[4];
#pragma unroll
    for (int r = 0; r < 4; ++r) {
        float vj = fwm * fast_tanh(a0s[r] + bia);
        float v1 = (c < 2) ? fw2 * fast_tanh(a1s[r] + bia1) : 0.f;
        float m2v = (c >= 12) ? vj : v1;
        float sh6  = __shfl(vj,  (lane & 48) | ((c + 6) & 15), 64);
        float shm2 = __shfl(m2v, (lane & 48) | ((c < 4 ? c + 12 : c - 4) & 15), 64);
        ang4[r] = PI_F * (vj + sh6 + shm2);
    }
    if (c < 6) {
#pragma unroll
        for (int r = 0; r < 4; ++r)
            ang_out[(size_t)(row_base + kh * 4 + r) * 6 + c] = ang4[r];
    }
}

// ---------------- circuit kernel (verbatim round 7, verified) ----------------

template<int M>
__device__ __forceinline__ void gateU(float (&re)[2], float (&im)[2], int lane,
                                      float ar, float ai, float br, float bi) {
    const bool hi = (lane & M) != 0;
    const float Ai = hi ? -ai : ai;
    const float Br = hi ? -br : br;
#pragma unroll
    for (int s = 0; s < 2; ++s) {
        float pre = xsh<M>(re[s]);
        float pim = xsh<M>(im[s]);
        float nr = ar * re[s] - Ai * im[s] + Br * pre - bi * pim;
        float ni = ar * im[s] + Ai * re[s] + Br * pim + bi * pre;
        re[s] = nr; im[s] = ni;
    }
}

template<int MC, int MT>
__device__ __forceinline__ void gateCRY(float (&re)[2], float (&im)[2], int lane, float c, float sn) {
    const bool c1 = (lane & MC) != 0;
    const float sg = (lane & MT) ? sn : -sn;
#pragma unroll
    for (int s = 0; s < 2; ++s) {
        float pre = xsh<MT>(re[s]);
        float pim = xsh<MT>(im[s]);
        float nr = fmaf(c, re[s], sg * pre);
        float ni = fmaf(c, im[s], sg * pim);
        re[s] = c1 ? nr : re[s];
        im[s] = c1 ? ni : im[s];
    }
}

template<int I>
__device__ __forceinline__ void l1gate(float (&re)[2], float (&im)[2], int lane,
                                       const float* __restrict__ ws) {
    constexpr int M = 32 >> I;
    gateU<M>(re, im, lane, ws[U_OFF + (6 + I) * 4 + 0], ws[U_OFF + (6 + I) * 4 + 1],
             ws[U_OFF + (6 + I) * 4 + 2], ws[U_OFF + (6 + I) * 4 + 3]);
}
template<int L, int P>
__device__ __forceinline__ void cryGate(float (&re)[2], float (&im)[2], int lane,
                                        const float* __restrict__ ws) {
    constexpr int MC = 32 >> (2 * P);
    constexpr int MT = 16 >> (2 * P);
    gateCRY<MC, MT>(re, im, lane, ws[CRY_OFF + (L * 3 + P) * 2 + 0],
                    ws[CRY_OFF + (L * 3 + P) * 2 + 1]);
}

__device__ __forceinline__ void buildState(const float (&ang)[6], int lane,
                                           const float* __restrict__ ws,
                                           float& reO, float& imO) {
    float pr, pi;
#pragma unroll
    for (int i = 0; i < 6; ++i) {
        float cq, sq;
        __sincosf(0.5f * ang[i], &sq, &cq);
        const float ar = ws[U_OFF + i * 4 + 0];
        const float ai = ws[U_OFF + i * 4 + 1];
        const float br = ws[U_OFF + i * 4 + 2];
        const float bi = ws[U_OFF + i * 4 + 3];
        float vloR = ar * cq + br * sq;
        float vloI = ai * cq + bi * sq;
        float vhiR = ar * sq - br * cq;
        float vhiI = bi * cq - ai * sq;
        bool hi = (lane & (32 >> i)) != 0;
        float vr = hi ? vhiR : vloR;
        float vi = hi ? vhiI : vloI;
        if (i == 0) { pr = vr; pi = vi; }
        else { float t = pr * vr - pi * vi; pi = pr * vi + pi * vr; pr = t; }
    }
    reO = pr; imO = pi;
}

__global__ __launch_bounds__(256, 8) void circuit_kernel(
    const float* __restrict__ ws, const float* __restrict__ ang_buf, float* __restrict__ out)
{
    const int lane = threadIdx.x & 63;
    const int wave = blockIdx.x * 4 + (threadIdx.x >> 6);  // 8192 waves
    const int s0 = wave * 2;

    const float* aA = ang_buf + (size_t)s0 * 6;
    float angA[6], angB[6];
#pragma unroll
    for (int j = 0; j < 6; ++j) { angA[j] = aA[j]; angB[j] = aA[6 + j]; }

    const int sigma = lane ^ ((lane >> 1) & 0x1F) ^ ((lane >> 5) & 1);

    float re[2], im[2];
    buildState(angA, lane, ws, re[0], im[0]);  // encoding + layer-0 rotations fused
    buildState(angB, lane, ws, re[1], im[1]);

    re[0] = __shfl(re[0], sigma, 64); im[0] = __shfl(im[0], sigma, 64);
    re[1] = __shfl(re[1], sigma, 64); im[1] = __shfl(im[1], sigma, 64);
    cryGate<0,0>(re, im, lane, ws); cryGate<0,1>(re, im, lane, ws); cryGate<0,2>(re, im, lane, ws);

    l1gate<0>(re, im, lane, ws); l1gate<1>(re, im, lane, ws); l1gate<2>(re, im, lane, ws);
    l1gate<3>(re, im, lane, ws); l1gate<4>(re, im, lane, ws); l1gate<5>(re, im, lane, ws);
    re[0] = __shfl(re[0], sigma, 64); im[0] = __shfl(im[0], sigma, 64);
    re[1] = __shfl(re[1], sigma, 64); im[1] = __shfl(im[1], sigma, 64);
    cryGate<1,0>(re, im, lane, ws); cryGate<1,1>(re, im, lane, ws); cryGate<1,2>(re, im, lane, ws);

#pragma unroll
    for (int s = 0; s < 2; ++s) {
        float p = fmaf(re[s], re[s], im[s] * im[s]);
        float q;
        q = xsh<1>(p);  p = (lane & 1)  ? (q - p) : (p + q);
        q = xsh<2>(p);  p = (lane & 2)  ? (q - p) : (p + q);
        q = xsh<4>(p);  p = (lane & 4)  ? (q - p) : (p + q);
        q = xsh<8>(p);  p = (lane & 8)  ? (q - p) : (p + q);
        q = xsh<16>(p); p = (lane & 16) ? (q - p) : (p + q);
        q = xsh<32>(p); p = (lane & 32) ? (q - p) : (p + q);
        if (__popc(lane) == 1)
            out[(size_t)(s0 + s) * 6 + (6 - __ffs(lane))] = p;
    }
}

extern "C" void kernel_launch(void* const* d_in, const int* in_sizes, int n_in,
                              void* d_out, int out_size, void* d_ws, size_t ws_size,
                              hipStream_t stream) {
    const float* f0 = (const float*)d_in[0];
    const float* W0 = (const float*)d_in[1];
    const float* b0 = (const float*)d_in[2];
    const float* f1 = (const float*)d_in[3];
    const float* W1 = (const float*)d_in[4];
    const float* b1 = (const float*)d_in[5];
    const float* f2 = (const float*)d_in[6];
    const float* W2 = (const float*)d_in[7];
    const float* b2 = (const float*)d_in[8];
    const float* qw = (const float*)d_in[9];
    const float* fl = (const float*)d_in[10];
    float* out = (float*)d_out;

    unsigned short* bt_hi = (unsigned short*)d_ws;
    unsigned short* bt_lo = bt_hi + 73728;
    float* wsf = (float*)d_ws;
    float* pacc = wsf + PACC_OFF;
    float* ang  = wsf + ANG_OFF;

    prep_bt<<<dim3(9, 32), 256, 0, stream>>>(W0, W1, W2, bt_hi, bt_lo);
    prep_consts<<<1, 64, 0, stream>>>(qw, wsf);
    gemm_kernel<<<1024, 256, 0, stream>>>(f0, f1, f2, bt_hi, bt_lo, pacc);
    reduce_kernel<<<256, 256, 0, stream>>>(b0, b1, b2, fl, pacc, ang);
    circuit_kernel<<<2048, 256, 0, stream>>>(wsf, ang, out);
}

// Round 11
// 59.687 us; speedup vs baseline: 1.3170x; 1.1413x over previous
//
#include <hip/hip_runtime.h>

#define PI_F 3.14159265358979323846f

#define D0 768
#define D1 512
#define D2 1024

// ---- d_ws layout ----
// ushort idx [0, 20480):      bA_hi [16 cols][1280 k]  (m0 cols 0-5 k<768; m1 cols 6-11 k>=768)
// ushort idx [20480, 40960):  bA_lo
// ushort idx [40960, 57344):  bB_hi [16 cols][1024 k]  (m2 cols 0-5)
// ushort idx [57344, 73728):  bB_lo
// float idx (from ws base):
#define U_OFF    36864                    // 12 gates * 4 floats
#define CRY_OFF  36912                    // 6 * 2 floats
#define PACC_OFF 36928                    // 9216 jobs * 256 floats = 9.4 MB
#define ANG_OFF  (PACC_OFF + 9216 * 256)  // 16384*6 floats

typedef short short8 __attribute__((ext_vector_type(8)));
typedef float f32x4 __attribute__((ext_vector_type(4)));
typedef unsigned int uint4v __attribute__((ext_vector_type(4)));

// ---------------- prep kernels ----------------

__global__ void prep_bt(const float* __restrict__ W0, const float* __restrict__ W1,
                        const float* __restrict__ W2, unsigned short* __restrict__ wsu) {
    int t = blockIdx.x * 256 + threadIdx.x;  // 0..36863 (grid 144)
    float v = 0.0f;
    unsigned short *dst_hi, *dst_lo;
    if (t < 20480) {            // bA: c = t/1280, k = t%1280
        int c = t / 1280, k = t - c * 1280;
        if (c < 6)       { if (k < 768)  v = W0[k * 6 + c]; }
        else if (c < 12) { if (k >= 768) v = W1[(k - 768) * 6 + (c - 6)]; }
        dst_hi = wsu + t; dst_lo = wsu + 20480 + t;
    } else {                    // bB: u = t-20480; c = u/1024, k = u%1024
        int u = t - 20480, c = u / 1024, k = u - c * 1024;
        if (c < 6) v = W2[k * 6 + c];
        dst_hi = wsu + 40960 + u; dst_lo = wsu + 57344 + u;
    }
    unsigned int uu = __float_as_uint(v);
    float hif = __uint_as_float(uu & 0xFFFF0000u);
    float lo = v - hif;  // exact residual
    *dst_hi = (unsigned short)(uu >> 16);
    *dst_lo = (unsigned short)(__float_as_uint(lo) >> 16);
}

__global__ void prep_consts(const float* __restrict__ qw, float* __restrict__ wsf) {
    int t = threadIdx.x;
    if (t < 12) {
        int g = t;  // layer*6 + qubit
        float ca, sa, cb, sb, cc, sc;
        sincosf(0.5f * qw[g * 3 + 0], &sa, &ca);
        sincosf(0.5f * qw[g * 3 + 1], &sb, &cb);
        sincosf(0.5f * qw[g * 3 + 2], &sc, &cc);
        float m00r = cb * ca, m00i = sb * sa;
        float m01r = -sb * ca, m01i = -cb * sa;
        float* u4 = wsf + U_OFF + g * 4;
        u4[0] = m00r * cc + m00i * sc;
        u4[1] = m00i * cc - m00r * sc;
        u4[2] = m01r * cc + m01i * sc;
        u4[3] = m01i * cc - m01r * sc;
    } else if (t < 18) {
        int k = t - 12;  // layer*3 + pair
        int l = k / 3, i = (k - l * 3) * 2;
        float c, s;
        sincosf(0.5f * qw[(l * 6 + i) * 3 + 1], &s, &c);
        wsf[CRY_OFF + k * 2 + 0] = c;
        wsf[CRY_OFF + k * 2 + 1] = s;
    }
}

// ---------------- helpers ----------------

__device__ __forceinline__ unsigned int pkhi(float x, float y) {
    return (__float_as_uint(x) >> 16) | (__float_as_uint(y) & 0xFFFF0000u);
}
__device__ __forceinline__ float truncbf(float x) {
    return __uint_as_float(__float_as_uint(x) & 0xFFFF0000u);
}
__device__ __forceinline__ void split8(float4 x0, float4 x1, short8& hi, short8& lo) {
    uint4v h, l;
    h[0] = pkhi(x0.x, x0.y); h[1] = pkhi(x0.z, x0.w);
    h[2] = pkhi(x1.x, x1.y); h[3] = pkhi(x1.z, x1.w);
    l[0] = pkhi(x0.x - truncbf(x0.x), x0.y - truncbf(x0.y));
    l[1] = pkhi(x0.z - truncbf(x0.z), x0.w - truncbf(x0.w));
    l[2] = pkhi(x1.x - truncbf(x1.x), x1.y - truncbf(x1.y));
    l[3] = pkhi(x1.z - truncbf(x1.z), x1.w - truncbf(x1.w));
    hi = __builtin_bit_cast(short8, h);
    lo = __builtin_bit_cast(short8, l);
}
__device__ __forceinline__ f32x4 mfma16(short8 a, short8 b, f32x4 c) {
    return __builtin_amdgcn_mfma_f32_16x16x32_bf16(a, b, c, 0, 0, 0);
}
__device__ __forceinline__ float fast_tanh(float x) {
    float e = __expf(2.0f * x);
    return 1.0f - 2.0f / (e + 1.0f);
}

template<int CTRL>
__device__ __forceinline__ float dppmov(float v) {
    return __int_as_float(__builtin_amdgcn_update_dpp(0, __float_as_int(v), CTRL, 0xF, 0xF, true));
}
template<int PAT>
__device__ __forceinline__ float swzf(float v) {
    return __int_as_float(__builtin_amdgcn_ds_swizzle(__float_as_int(v), PAT));
}
template<int M>
__device__ __forceinline__ float xsh(float v) {
    if constexpr (M == 1)       return dppmov<0xB1>(v);
    else if constexpr (M == 2)  return dppmov<0x4E>(v);
    else if constexpr (M == 4)  return swzf<0x101F>(v);
    else if constexpr (M == 8)  return dppmov<0x128>(v);
    else if constexpr (M == 16) return swzf<0x401F>(v);
    else                        return __shfl_xor(v, 32, 64);
}

// ---------------- GEMM: modality-aligned split-K=9, dual chains, global partials ----------------
// job j = 4*blockIdx + wid; m = j/9 (16-row tile), sl = j%9 (256-k slice of one modality).
// sl 0-2: m0; sl 3-4: m1; sl 5-8: m2. Two independent chains (tiles 0-3 / 4-7).

__global__ __launch_bounds__(256, 6) void gemm_kernel(
    const float* __restrict__ f0, const float* __restrict__ f1, const float* __restrict__ f2,
    const unsigned short* __restrict__ wsu, float* __restrict__ pacc)
{
    const int tid = threadIdx.x;
    const int lane = tid & 63;
    const int j = blockIdx.x * 4 + (tid >> 6);   // 0..9215
    const int m = j / 9;
    const int sl = j - m * 9;
    const int c = lane & 15;
    const int kh = lane >> 4;

    const size_t rb = m * 16 + c;
    const float* a;
    const unsigned short *bh, *bl;
    if (sl < 3) {
        a  = f0 + rb * D0 + sl * 256;
        bh = wsu + c * 1280 + sl * 256;
        bl = wsu + 20480 + c * 1280 + sl * 256;
    } else if (sl < 5) {
        a  = f1 + rb * D1 + (sl - 3) * 256;
        bh = wsu + c * 1280 + 768 + (sl - 3) * 256;
        bl = wsu + 20480 + c * 1280 + 768 + (sl - 3) * 256;
    } else {
        a  = f2 + rb * D2 + (sl - 5) * 256;
        bh = wsu + 40960 + c * 1024 + (sl - 5) * 256;
        bl = wsu + 57344 + c * 1024 + (sl - 5) * 256;
    }
    a += kh * 8; bh += kh * 8; bl += kh * 8;

    f32x4 accP = {0.f, 0.f, 0.f, 0.f};
    f32x4 accQ = {0.f, 0.f, 0.f, 0.f};

#pragma unroll
    for (int tt = 0; tt < 4; ++tt) {
        const int ko = tt * 32;
        // 8 independent A loads + 4 B loads per round (two chains)
        float4 p0 = *(const float4*)(a + ko);
        float4 p1 = *(const float4*)(a + ko + 4);
        float4 q0 = *(const float4*)(a + 128 + ko);
        float4 q1 = *(const float4*)(a + 128 + ko + 4);
        short8 pbh = *(const short8*)(bh + ko);
        short8 pbl = *(const short8*)(bl + ko);
        short8 qbh = *(const short8*)(bh + 128 + ko);
        short8 qbl = *(const short8*)(bl + 128 + ko);
        short8 phi, plo, qhi, qlo;
        split8(p0, p1, phi, plo);
        split8(q0, q1, qhi, qlo);
        accP = mfma16(phi, pbh, accP);
        accP = mfma16(plo, pbh, accP);
        accP = mfma16(phi, pbl, accP);
        accQ = mfma16(qhi, qbh, accQ);
        accQ = mfma16(qlo, qbh, accQ);
        accQ = mfma16(qhi, qbl, accQ);
    }

    float* pj = pacc + (size_t)j * 256;
#pragma unroll
    for (int r = 0; r < 4; ++r)
        pj[r * 64 + lane] = accP[r] + accQ[r];
}

// ---------------- reduce + epilogue ----------------
// Tile A cols: 0-5 = m0, 6-11 = m1. Tile B cols: 0-5 = m2 (same lane as output col!).

__global__ __launch_bounds__(256) void reduce_kernel(
    const float* __restrict__ b0, const float* __restrict__ b1, const float* __restrict__ b2,
    const float* __restrict__ fl, const float* __restrict__ pacc, float* __restrict__ ang_out)
{
    const int tid = threadIdx.x;
    const int lane = tid & 63;
    const int m = blockIdx.x * 4 + (tid >> 6);   // 0..1023
    const int row_base = m * 16;
    const int c = lane & 15;
    const int kh = lane >> 4;

    const float* pm = pacc + (size_t)m * 9 * 256;
    float aA[4], aB[4];
#pragma unroll
    for (int r = 0; r < 4; ++r) {
        float sA = 0.f, sB = 0.f;
#pragma unroll
        for (int sl = 0; sl < 5; ++sl) sA += pm[sl * 256 + r * 64 + lane];
#pragma unroll
        for (int sl = 5; sl < 9; ++sl) sB += pm[sl * 256 + r * 64 + lane];
        aA[r] = sA; aB[r] = sB;
    }

    float l0 = fl[0], l1 = fl[1], l2 = fl[2];
    float mx = fmaxf(l0, fmaxf(l1, l2));
    float e0 = __expf(l0 - mx), e1 = __expf(l1 - mx), e2 = __expf(l2 - mx);
    float inv = 1.0f / (e0 + e1 + e2);
    float fw0 = e0 * inv, fw1 = e1 * inv, fw2 = e2 * inv;

    float biaA = 0.f, fwmA = 0.f;
    if (c < 6)       { biaA = b0[c];     fwmA = fw0; }
    else if (c < 12) { biaA = b1[c - 6]; fwmA = fw1; }
    float biaB = (c < 6) ? b2[c] : 0.f;

#pragma unroll
    for (int r = 0; r < 4; ++r) {
        float vA = fwmA * fast_tanh(aA[r] + biaA);
        float vB = (c < 6) ? fw2 * fast_tanh(aB[r] + biaB) : 0.f;
        float sh6 = __shfl(vA, (lane & 48) | ((c + 6) & 15), 64);
        if (c < 6)
            ang_out[(size_t)(row_base + kh * 4 + r) * 6 + c] = PI_F * (vA + sh6 + vB);
    }
}

// ---------------- circuit kernel (verbatim round 10, verified) ----------------

template<int M>
__device__ __forceinline__ void gateU(float (&re)[2], float (&im)[2], int lane,
                                      float ar, float ai, float br, float bi) {
    const bool hi = (lane & M) != 0;
    const float Ai = hi ? -ai : ai;
    const float Br = hi ? -br : br;
#pragma unroll
    for (int s = 0; s < 2; ++s) {
        float pre = xsh<M>(re[s]);
        float pim = xsh<M>(im[s]);
        float nr = ar * re[s] - Ai * im[s] + Br * pre - bi * pim;
        float ni = ar * im[s] + Ai * re[s] + Br * pim + bi * pre;
        re[s] = nr; im[s] = ni;
    }
}

template<int MC, int MT>
__device__ __forceinline__ void gateCRY(float (&re)[2], float (&im)[2], int lane, float c, float sn) {
    const bool c1 = (lane & MC) != 0;
    const float sg = (lane & MT) ? sn : -sn;
#pragma unroll
    for (int s = 0; s < 2; ++s) {
        float pre = xsh<MT>(re[s]);
        float pim = xsh<MT>(im[s]);
        float nr = fmaf(c, re[s], sg * pre);
        float ni = fmaf(c, im[s], sg * pim);
        re[s] = c1 ? nr : re[s];
        im[s] = c1 ? ni : im[s];
    }
}

template<int I>
__device__ __forceinline__ void l1gate(float (&re)[2], float (&im)[2], int lane,
                                       const float* __restrict__ ws) {
    constexpr int M = 32 >> I;
    gateU<M>(re, im, lane, ws[U_OFF + (6 + I) * 4 + 0], ws[U_OFF + (6 + I) * 4 + 1],
             ws[U_OFF + (6 + I) * 4 + 2], ws[U_OFF + (6 + I) * 4 + 3]);
}
template<int L, int P>
__device__ __forceinline__ void cryGate(float (&re)[2], float (&im)[2], int lane,
                                        const float* __restrict__ ws) {
    constexpr int MC = 32 >> (2 * P);
    constexpr int MT = 16 >> (2 * P);
    gateCRY<MC, MT>(re, im, lane, ws[CRY_OFF + (L * 3 + P) * 2 + 0],
                    ws[CRY_OFF + (L * 3 + P) * 2 + 1]);
}

__device__ __forceinline__ void buildState(const float (&ang)[6], int lane,
                                           const float* __restrict__ ws,
                                           float& reO, float& imO) {
    float pr, pi;
#pragma unroll
    for (int i = 0; i < 6; ++i) {
        float cq, sq;
        __sincosf(0.5f * ang[i], &sq, &cq);
        const float ar = ws[U_OFF + i * 4 + 0];
        const float ai = ws[U_OFF + i * 4 + 1];
        const float br = ws[U_OFF + i * 4 + 2];
        const float bi = ws[U_OFF + i * 4 + 3];
        float vloR = ar * cq + br * sq;
        float vloI = ai * cq + bi * sq;
        float vhiR = ar * sq - br * cq;
        float vhiI = bi * cq - ai * sq;
        bool hi = (lane & (32 >> i)) != 0;
        float vr = hi ? vhiR : vloR;
        float vi = hi ? vhiI : vloI;
        if (i == 0) { pr = vr; pi = vi; }
        else { float t = pr * vr - pi * vi; pi = pr * vi + pi * vr; pr = t; }
    }
    reO = pr; imO = pi;
}

__global__ __launch_bounds__(256, 8) void circuit_kernel(
    const float* __restrict__ ws, const float* __restrict__ ang_buf, float* __restrict__ out)
{
    const int lane = threadIdx.x & 63;
    const int wave = blockIdx.x * 4 + (threadIdx.x >> 6);  // 8192 waves
    const int s0 = wave * 2;

    const float* aA = ang_buf + (size_t)s0 * 6;
    float angA[6], angB[6];
#pragma unroll
    for (int j = 0; j < 6; ++j) { angA[j] = aA[j]; angB[j] = aA[6 + j]; }

    const int sigma = lane ^ ((lane >> 1) & 0x1F) ^ ((lane >> 5) & 1);

    float re[2], im[2];
    buildState(angA, lane, ws, re[0], im[0]);  // encoding + layer-0 rotations fused
    buildState(angB, lane, ws, re[1], im[1]);

    re[0] = __shfl(re[0], sigma, 64); im[0] = __shfl(im[0], sigma, 64);
    re[1] = __shfl(re[1], sigma, 64); im[1] = __shfl(im[1], sigma, 64);
    cryGate<0,0>(re, im, lane, ws); cryGate<0,1>(re, im, lane, ws); cryGate<0,2>(re, im, lane, ws);

    l1gate<0>(re, im, lane, ws); l1gate<1>(re, im, lane, ws); l1gate<2>(re, im, lane, ws);
    l1gate<3>(re, im, lane, ws); l1gate<4>(re, im, lane, ws); l1gate<5>(re, im, lane, ws);
    re[0] = __shfl(re[0], sigma, 64); im[0] = __shfl(im[0], sigma, 64);
    re[1] = __shfl(re[1], sigma, 64); im[1] = __shfl(im[1], sigma, 64);
    cryGate<1,0>(re, im, lane, ws); cryGate<1,1>(re, im, lane, ws); cryGate<1,2>(re, im, lane, ws);

#pragma unroll
    for (int s = 0; s < 2; ++s) {
        float p = fmaf(re[s], re[s], im[s] * im[s]);
        float q;
        q = xsh<1>(p);  p = (lane & 1)  ? (q - p) : (p + q);
        q = xsh<2>(p);  p = (lane & 2)  ? (q - p) : (p + q);
        q = xsh<4>(p);  p = (lane & 4)  ? (q - p) : (p + q);
        q = xsh<8>(p);  p = (lane & 8)  ? (q - p) : (p + q);
        q = xsh<16>(p); p = (lane & 16) ? (q - p) : (p + q);
        q = xsh<32>(p); p = (lane & 32) ? (q - p) : (p + q);
        if (__popc(lane) == 1)
            out[(size_t)(s0 + s) * 6 + (6 - __ffs(lane))] = p;
    }
}

extern "C" void kernel_launch(void* const* d_in, const int* in_sizes, int n_in,
                              void* d_out, int out_size, void* d_ws, size_t ws_size,
                              hipStream_t stream) {
    const float* f0 = (const float*)d_in[0];
    const float* W0 = (const float*)d_in[1];
    const float* b0 = (const float*)d_in[2];
    const float* f1 = (const float*)d_in[3];
    const float* W1 = (const float*)d_in[4];
    const float* b1 = (const float*)d_in[5];
    const float* f2 = (const float*)d_in[6];
    const float* W2 = (const float*)d_in[7];
    const float* b2 = (const float*)d_in[8];
    const float* qw = (const float*)d_in[9];
    const float* fl = (const float*)d_in[10];
    float* out = (float*)d_out;

    unsigned short* wsu = (unsigned short*)d_ws;
    float* wsf = (float*)d_ws;
    float* pacc = wsf + PACC_OFF;
    float* ang  = wsf + ANG_OFF;

    prep_bt<<<144, 256, 0, stream>>>(W0, W1, W2, wsu);
    prep_consts<<<1, 64, 0, stream>>>(qw, wsf);
    gemm_kernel<<<2304, 256, 0, stream>>>(f0, f1, f2, wsu, pacc);
    reduce_kernel<<<256, 256, 0, stream>>>(b0, b1, b2, fl, pacc, ang);
    circuit_kernel<<<2048, 256, 0, stream>>>(wsf, ang, out);
}